// Round 2
// baseline (6607.237 us; speedup 1.0000x reference)
//
#include <hip/hip_runtime.h>

#define DD 512
#define BB 64
#define VV 32000
#define TT 32
#define GRID 256
#define NTHR 256
#define NTILE 500  // 32000 / 64

typedef __attribute__((ext_vector_type(8))) short short8;
typedef __attribute__((ext_vector_type(4))) float f32x4;
typedef __attribute__((ext_vector_type(4))) unsigned short ushort4v;

__device__ __forceinline__ float sigm(float x) { return 1.0f / (1.0f + __expf(-x)); }
__device__ __forceinline__ float ftanh(float x) {
  float e = __expf(2.0f * x);
  return 1.0f - 2.0f / (e + 1.0f);
}
__device__ __forceinline__ unsigned short f2bf(float f) {
  unsigned int u = __float_as_uint(f);
  u = (u + 0x7FFFu + ((u >> 16) & 1u)) >> 16;
  return (unsigned short)u;
}

struct CellS { float4 xs4[16][128]; float4 hs4[16][128]; float gv[8][4][16]; };  // 67584 B
struct AttnS { float fsc[512]; float hs[512]; float wv[256]; };                  // 5120 B
struct ZS    { float4 hs4[16][128]; float4 cs4[16][128]; float zp[2][16][8]; };  // 66560 B
struct LnS   { float zs[512]; float rs[256]; float rq[256]; };                   // 4096 B

// ---- device-scope generation barrier (all GRID blocks co-resident) ----
__device__ __forceinline__ void gridsync(unsigned* bar) {
  __syncthreads();  // drains this block's vmem (compiler emits vmcnt(0))
  if (threadIdx.x == 0) {
    __threadfence();  // release this block's writes to agent scope
    unsigned* cnt = bar;
    unsigned* gen = bar + 32;  // separate cacheline
    unsigned g = __hip_atomic_load(gen, __ATOMIC_RELAXED, __HIP_MEMORY_SCOPE_AGENT);
    unsigned old = __hip_atomic_fetch_add(cnt, 1u, __ATOMIC_ACQ_REL, __HIP_MEMORY_SCOPE_AGENT);
    if (old == GRID - 1) {
      __hip_atomic_store(cnt, 0u, __ATOMIC_RELAXED, __HIP_MEMORY_SCOPE_AGENT);
      __hip_atomic_fetch_add(gen, 1u, __ATOMIC_ACQ_REL, __HIP_MEMORY_SCOPE_AGENT);
    } else {
      while (__hip_atomic_load(gen, __ATOMIC_ACQUIRE, __HIP_MEMORY_SCOPE_AGENT) == g)
        __builtin_amdgcn_s_sleep(2);
    }
    __threadfence();  // acquire side
  }
  __syncthreads();
}

__global__ void bar_init_k(unsigned* bar) { bar[threadIdx.x] = 0u; }

// ---- phase: LSTM cell (all 256 blocks: 4 bgroups x 64 colgroups) ----
__device__ __forceinline__ void cell_phase(char* smemraw, int bid,
    const float* __restrict__ Wih, const float* __restrict__ Whh,
    const float* __restrict__ bih, const float* __restrict__ bhh,
    const float* __restrict__ emb, const float* __restrict__ h_old,
    const float* __restrict__ c_old, float* __restrict__ h_new, float* __restrict__ c_new)
{
  CellS& S = *reinterpret_cast<CellS*>(smemraw);
  int tid = threadIdx.x;
  int bg = bid >> 6, cg = bid & 63;
  int b0 = bg * 16, d0 = cg * 8;
  const float4* ep = (const float4*)emb;
  const float4* hp = (const float4*)h_old;
  for (int i = tid; i < 2048; i += 256) {
    int b = i >> 7, k4 = i & 127;
    S.xs4[b][k4] = ep[(size_t)(b0 + b) * 128 + k4];
    S.hs4[b][k4] = hp[(size_t)(b0 + b) * 128 + k4];
  }
  __syncthreads();
  int rl = tid & 31, dl = rl >> 2, gate = rl & 3, bl = tid >> 5;
  int r = gate * 512 + d0 + dl;  // gate order i,f,g,o
  const float4* wi = (const float4*)(Wih + (size_t)r * 512);
  const float4* wh = (const float4*)(Whh + (size_t)r * 512);
  float acc0 = 0.f, acc1 = 0.f;
#pragma unroll 4
  for (int k4 = 0; k4 < 128; k4++) {
    float4 a = wi[k4], w = wh[k4];
    float4 x0 = S.xs4[bl][k4], x1 = S.xs4[bl + 8][k4];
    float4 h0 = S.hs4[bl][k4], h1 = S.hs4[bl + 8][k4];
    acc0 = fmaf(a.x, x0.x, acc0); acc0 = fmaf(a.y, x0.y, acc0);
    acc0 = fmaf(a.z, x0.z, acc0); acc0 = fmaf(a.w, x0.w, acc0);
    acc0 = fmaf(w.x, h0.x, acc0); acc0 = fmaf(w.y, h0.y, acc0);
    acc0 = fmaf(w.z, h0.z, acc0); acc0 = fmaf(w.w, h0.w, acc0);
    acc1 = fmaf(a.x, x1.x, acc1); acc1 = fmaf(a.y, x1.y, acc1);
    acc1 = fmaf(a.z, x1.z, acc1); acc1 = fmaf(a.w, x1.w, acc1);
    acc1 = fmaf(w.x, h1.x, acc1); acc1 = fmaf(w.y, h1.y, acc1);
    acc1 = fmaf(w.z, h1.z, acc1); acc1 = fmaf(w.w, h1.w, acc1);
  }
  float bias = bih[r] + bhh[r];
  S.gv[dl][gate][bl] = acc0 + bias;
  S.gv[dl][gate][bl + 8] = acc1 + bias;
  __syncthreads();
  if (tid < 128) {
    int b = tid & 15, dx = tid >> 4;
    float gi = S.gv[dx][0][b], gf = S.gv[dx][1][b], gg = S.gv[dx][2][b], go = S.gv[dx][3][b];
    size_t idx = (size_t)(b0 + b) * 512 + d0 + dx;
    float c2 = sigm(gf) * c_old[idx] + sigm(gi) * ftanh(gg);
    c_new[idx] = c2;
    h_new[idx] = sigm(go) * ftanh(c2);
  }
}

// ---- phase: fused attention, blocks 0..127 = (b, jhalf); Z computed fully in-block ----
__device__ __forceinline__ void attn_phase(char* smemraw, int bid,
    const float* __restrict__ feats, const float* __restrict__ h, float* __restrict__ ctxp)
{
  AttnS& S = *reinterpret_cast<AttnS*>(smemraw);
  int tid = threadIdx.x;
  int b = bid >> 1, jh = bid & 1;
  const float LOG2E = 1.44269504088896f;
  float f0 = feats[b * 512 + tid], f1 = feats[b * 512 + 256 + tid];
  S.fsc[tid] = f0 * LOG2E;
  S.fsc[256 + tid] = f1 * LOG2E;
  S.hs[tid] = h[b * 512 + tid];
  S.hs[256 + tid] = h[b * 512 + 256 + tid];
  __syncthreads();
  // Z_j = sum_i exp(f_i * h_j), full i-range, for my 256 j's
  int j = jh * 256 + tid;
  float hj = S.hs[j];
  float Z = 0.f;
#pragma unroll 8
  for (int i = 0; i < 512; i++) Z += exp2f(S.fsc[i] * hj);
  S.wv[tid] = feats[b * 512 + j] / Z;
  __syncthreads();
  // ctx-partial over my j-half for all 512 i
#pragma unroll
  for (int rep = 0; rep < 2; rep++) {
    int i = rep * 256 + tid;
    float fi = S.fsc[i];
    float acc = 0.f;
#pragma unroll 8
    for (int jj = 0; jj < 256; jj++)
      acc += exp2f(fi * S.hs[jh * 256 + jj]) * S.wv[jj];
    ctxp[((size_t)jh * 64 + b) * 512 + i] = acc;
  }
}

// ---- phase: z = [h|ctx] @ Whc.T + bhc (all 256 blocks) ----
__device__ __forceinline__ void zgemm_phase(char* smemraw, int bid,
    const float* __restrict__ h, const float* __restrict__ ctxp,
    const float* __restrict__ Whc, const float* __restrict__ bhc, float* __restrict__ z)
{
  ZS& S = *reinterpret_cast<ZS*>(smemraw);
  int tid = threadIdx.x;
  int bg = bid >> 6, cg = bid & 63;
  int b0 = bg * 16, d0 = cg * 8;
  const float4* hp = (const float4*)h;
  const float4* cp = (const float4*)ctxp;
  for (int i = tid; i < 2048; i += 256) {
    int b = i >> 7, k4 = i & 127;
    S.hs4[b][k4] = hp[(size_t)(b0 + b) * 128 + k4];
    float4 s0 = cp[((size_t)0 * 64 + b0 + b) * 128 + k4];
    float4 s1 = cp[((size_t)1 * 64 + b0 + b) * 128 + k4];
    float4 s; s.x = s0.x + s1.x; s.y = s0.y + s1.y; s.z = s0.z + s1.z; s.w = s0.w + s1.w;
    S.cs4[b][k4] = s;
  }
  __syncthreads();
  int dl = tid & 7, b = (tid >> 3) & 15, kh = tid >> 7;
  int dcol = d0 + dl;
  const float4* wr = (const float4*)(Whc + (size_t)dcol * 1024 + (size_t)kh * 512);
  float4 (*src)[128] = kh ? S.cs4 : S.hs4;
  float acc = 0.f;
#pragma unroll 4
  for (int k4 = 0; k4 < 128; k4++) {
    float4 w = wr[k4], x = src[b][k4];
    acc = fmaf(w.x, x.x, acc); acc = fmaf(w.y, x.y, acc);
    acc = fmaf(w.z, x.z, acc); acc = fmaf(w.w, x.w, acc);
  }
  S.zp[kh][b][dl] = acc;
  __syncthreads();
  if (tid < 128) {
    int bb = tid >> 3, dd = tid & 7;
    z[(size_t)(b0 + bb) * 512 + d0 + dd] = S.zp[0][bb][dd] + S.zp[1][bb][dd] + bhc[d0 + dd];
  }
}

// ---- phase: LayerNorm + tanh -> emb fp32 + bf16 (blocks 0..63) ----
__device__ __forceinline__ void ln_phase(char* smemraw, int b,
    const float* __restrict__ z, const float* __restrict__ gamma, const float* __restrict__ beta,
    float* __restrict__ emb, unsigned short* __restrict__ emb_bf)
{
  LnS& S = *reinterpret_cast<LnS*>(smemraw);
  int tid = threadIdx.x;
  float a = z[b * 512 + tid], d = z[b * 512 + 256 + tid];
  S.zs[tid] = a; S.zs[tid + 256] = d;
  S.rs[tid] = a + d; S.rq[tid] = a * a + d * d;
  __syncthreads();
  for (int s = 128; s > 0; s >>= 1) {
    if (tid < s) { S.rs[tid] += S.rs[tid + s]; S.rq[tid] += S.rq[tid + s]; }
    __syncthreads();
  }
  float mean = S.rs[0] * (1.0f / 512.0f);
  float var = S.rq[0] * (1.0f / 512.0f) - mean * mean;
  float rstd = rsqrtf(var + 1e-5f);
  for (int d2 = tid; d2 < 512; d2 += 256) {
    float xn = (S.zs[d2] - mean) * rstd;
    float e = ftanh(xn * gamma[d2] + beta[d2]);
    emb[b * 512 + d2] = e;
    emb_bf[b * 512 + d2] = f2bf(e);
  }
}

// ---- one logits tile: 64 vocab columns, bf16 MFMA 16x16x32 (4 waves / 256 thr) ----
__device__ __forceinline__ void logits_tile(const unsigned short* __restrict__ emb_bf,
    const unsigned short* __restrict__ vocab_bf, const float* __restrict__ vbias,
    float* __restrict__ out, int q)
{
  if (q >= NTILE) return;
  int n0 = q * 64;
  int w = threadIdx.x >> 6, l = threadIdx.x & 63;
  int lm = l & 15, kb = l >> 4;
  int m = w * 16 + lm;
  f32x4 acc[4] = {};
  const short8* ap = (const short8*)(emb_bf + (size_t)m * 512);
#pragma unroll 4
  for (int kt = 0; kt < 16; kt++) {
    short8 a = ap[kt * 4 + kb];
#pragma unroll
    for (int nt = 0; nt < 4; nt++) {
      const short8* bp = (const short8*)(vocab_bf + (size_t)(n0 + nt * 16 + lm) * 512);
      short8 bv = bp[kt * 4 + kb];
      acc[nt] = __builtin_amdgcn_mfma_f32_16x16x32_bf16(a, bv, acc[nt], 0, 0, 0);
    }
  }
  int rbase = w * 16 + kb * 4;  // C/D layout: col = lane&15, row = (lane>>4)*4 + reg
#pragma unroll
  for (int nt = 0; nt < 4; nt++) {
    int v = n0 + nt * 16 + lm;
    float bias = vbias[v];
#pragma unroll
    for (int r = 0; r < 4; r++) {
      out[(size_t)(rbase + r) * 32000 + v] = acc[nt][r] + bias;
    }
  }
}

// ---- the persistent kernel ----
__global__ __launch_bounds__(256, 1) void persist_k(
    const float* __restrict__ feats, const float* __restrict__ Wih, const float* __restrict__ Whh,
    const float* __restrict__ bih, const float* __restrict__ bhh,
    const float* __restrict__ Whc, const float* __restrict__ bhc,
    const float* __restrict__ gam, const float* __restrict__ bet,
    const float* __restrict__ vemb, const float* __restrict__ vbias,
    unsigned short* vocab_bf, float* hA, float* hB, float* cA, float* cB,
    float* emb, float* zb, unsigned short* ebf0, unsigned short* ebf1,
    float* ctxp, float* out, unsigned* bar)
{
  __shared__ __align__(16) char smem[sizeof(CellS)];
  const int bid = blockIdx.x, tid = threadIdx.x;

  // phase V: vocab fp32->bf16 (4,096,000 float4s) + state init
  {
    const float4* vp = (const float4*)vemb;
    ushort4v* op = (ushort4v*)vocab_bf;
    for (int i = bid * NTHR + tid; i < VV * DD / 4; i += GRID * NTHR) {
      float4 x = vp[i];
      ushort4v y;
      y.x = f2bf(x.x); y.y = f2bf(x.y); y.z = f2bf(x.z); y.w = f2bf(x.w);
      op[i] = y;
    }
    for (int i = bid * NTHR + tid; i < BB * DD; i += GRID * NTHR) {
      float f = feats[i];
      hA[i] = f; cA[i] = f;
      emb[i] = vemb[i & (DD - 1)];
    }
  }
  gridsync(bar);

  for (int t = 0; t < TT; t++) {
    float* ho = (t & 1) ? hB : hA; float* hn = (t & 1) ? hA : hB;
    float* co = (t & 1) ? cB : cA; float* cn = (t & 1) ? cA : cB;
    unsigned short* ebf_cur  = (t & 1) ? ebf1 : ebf0;
    unsigned short* ebf_prev = (t & 1) ? ebf0 : ebf1;  // = step (t-1)'s buffer
    float* out_prev = out + (size_t)(t - 1) * BB * VV;

    // P1: cell(t) — all blocks
    cell_phase(smem, bid, Wih, Whh, bih, bhh, emb, ho, co, hn, cn);
    gridsync(bar);

    // P2: attn(t) on blocks 0..127; logits(t-1) tiles 0..255 on blocks 128..255
    if (bid < 128) {
      attn_phase(smem, bid, feats, hn, ctxp);
    } else if (t >= 1) {
      int idx = bid - 128;
      logits_tile(ebf_prev, vocab_bf, vbias, out_prev, idx * 2);
      logits_tile(ebf_prev, vocab_bf, vbias, out_prev, idx * 2 + 1);
    }
    gridsync(bar);

    // P3: zgemm(t) — all blocks
    zgemm_phase(smem, bid, hn, ctxp, Whc, bhc, zb);
    gridsync(bar);

    // P4: ln(t) on blocks 0..63; logits(t-1) tiles 256..499 on blocks 64..255
    if (bid < 64) {
      ln_phase(smem, bid, zb, gam, bet, emb, ebf_cur);
    } else if (t >= 1) {
      int idx = bid - 64;
      if (idx < 52) {
        logits_tile(ebf_prev, vocab_bf, vbias, out_prev, 256 + 2 * idx);
        logits_tile(ebf_prev, vocab_bf, vbias, out_prev, 257 + 2 * idx);
      } else {
        logits_tile(ebf_prev, vocab_bf, vbias, out_prev, 360 + (idx - 52));
      }
    }
    gridsync(bar);
  }

  // drain: logits(31) — all blocks, 2 tiles each
  {
    float* o31 = out + (size_t)(TT - 1) * BB * VV;
    logits_tile(ebf1, vocab_bf, vbias, o31, bid * 2);
    logits_tile(ebf1, vocab_bf, vbias, o31, bid * 2 + 1);
  }
}

extern "C" void kernel_launch(void* const* d_in, const int* in_sizes, int n_in,
                              void* d_out, int out_size, void* d_ws, size_t ws_size,
                              hipStream_t stream) {
  const float* feats = (const float*)d_in[0];
  const float* Wih   = (const float*)d_in[1];
  const float* Whh   = (const float*)d_in[2];
  const float* bih   = (const float*)d_in[3];
  const float* bhh   = (const float*)d_in[4];
  const float* Whc   = (const float*)d_in[5];
  const float* bhc   = (const float*)d_in[6];
  const float* gam   = (const float*)d_in[7];
  const float* bet   = (const float*)d_in[8];
  const float* vemb  = (const float*)d_in[9];
  const float* vbias = (const float*)d_in[10];
  float* out = (float*)d_out;

  char* p = (char*)d_ws;
  unsigned short* vocab_bf = (unsigned short*)p; p += (size_t)VV * DD * 2;  // 32.77 MB
  float* hA  = (float*)p; p += BB * DD * 4;
  float* hB  = (float*)p; p += BB * DD * 4;
  float* cA  = (float*)p; p += BB * DD * 4;
  float* cB  = (float*)p; p += BB * DD * 4;
  float* emb = (float*)p; p += BB * DD * 4;
  float* zb  = (float*)p; p += BB * DD * 4;
  unsigned short* ebf0 = (unsigned short*)p; p += BB * DD * 2;
  unsigned short* ebf1 = (unsigned short*)p; p += BB * DD * 2;
  float* ctxp = (float*)p; p += (size_t)2 * BB * DD * 4;
  unsigned* bar = (unsigned*)p; p += 256;

  bar_init_k<<<1, 64, 0, stream>>>(bar);
  persist_k<<<GRID, NTHR, 0, stream>>>(feats, Wih, Whh, bih, bhh, Whc, bhc, gam, bet,
                                       vemb, vbias, vocab_bf, hA, hB, cA, cB, emb, zb,
                                       ebf0, ebf1, ctxp, out, bar);
}

// Round 3
// 4148.669 us; speedup vs baseline: 1.5926x; 1.5926x over previous
//
#include <hip/hip_runtime.h>

#define DD 512
#define BB 64
#define VV 32000
#define TT 32
#define GRID 256
#define NTHR 256
#define NTILE 500  // 32000 / 64

typedef __attribute__((ext_vector_type(8))) short short8;
typedef __attribute__((ext_vector_type(4))) float f32x4;
typedef unsigned long long u64;

__device__ __forceinline__ float sigm(float x) { return 1.0f / (1.0f + __expf(-x)); }
__device__ __forceinline__ float ftanh(float x) {
  float e = __expf(2.0f * x);
  return 1.0f - 2.0f / (e + 1.0f);
}
__device__ __forceinline__ unsigned short f2bf(float f) {
  unsigned int u = __float_as_uint(f);
  u = (u + 0x7FFFu + ((u >> 16) & 1u)) >> 16;
  return (unsigned short)u;
}

// ---- coherent (LLC round-trip, sc0 sc1) accessors for mutable cross-block state ----
__device__ __forceinline__ void st_u32(unsigned* p, unsigned v) {
  __hip_atomic_store(p, v, __ATOMIC_RELAXED, __HIP_MEMORY_SCOPE_AGENT);
}
__device__ __forceinline__ unsigned ld_u32c(const unsigned* p) {
  return __hip_atomic_load(p, __ATOMIC_RELAXED, __HIP_MEMORY_SCOPE_AGENT);
}
__device__ __forceinline__ void st_u64c(u64* p, u64 v) {
  __hip_atomic_store(p, v, __ATOMIC_RELAXED, __HIP_MEMORY_SCOPE_AGENT);
}
__device__ __forceinline__ u64 ld_u64c(const u64* p) {
  return __hip_atomic_load(p, __ATOMIC_RELAXED, __HIP_MEMORY_SCOPE_AGENT);
}
__device__ __forceinline__ void st_f32(float* p, float v) { st_u32((unsigned*)p, __float_as_uint(v)); }
__device__ __forceinline__ float ld_f32(const float* p) { return __uint_as_float(ld_u32c((const unsigned*)p)); }
__device__ __forceinline__ float2 u64_to_f2(u64 v) {
  float2 r; r.x = __uint_as_float((unsigned)v); r.y = __uint_as_float((unsigned)(v >> 32)); return r;
}
__device__ __forceinline__ u64 f2_to_u64(float a, float b) {
  return (u64)__float_as_uint(a) | ((u64)__float_as_uint(b) << 32);
}

struct CellS { float4 xs4[16][128]; float4 hs4[16][128]; float gv[8][4][16]; };  // 67584 B
struct AttnS { float fsc[512]; float hs[512]; float wv[256]; };
struct ZS    { float4 hs4[16][128]; float4 cs4[16][128]; float zp[2][16][8]; };
struct LnS   { float zs[512]; float rs[256]; float rq[256]; };
union SmemU {
  CellS cell; AttnS attn; ZS z; LnS ln;
  unsigned short ebf[64 * 520];  // logits A staging, padded rows (66560 B)
};

// ---- fence-free grid barrier: monotonic arrival counter, relaxed atomics only ----
__device__ __forceinline__ void gridsync(unsigned* bar, unsigned& epoch) {
  __syncthreads();  // drains this block's vmem (incl. sc1 stores -> at LLC)
  if (threadIdx.x == 0) {
    asm volatile("s_waitcnt vmcnt(0)" ::: "memory");
    __hip_atomic_fetch_add(bar, 1u, __ATOMIC_RELAXED, __HIP_MEMORY_SCOPE_AGENT);
    epoch += GRID;
    while (__hip_atomic_load(bar, __ATOMIC_RELAXED, __HIP_MEMORY_SCOPE_AGENT) < epoch)
      __builtin_amdgcn_s_sleep(2);
  }
  __syncthreads();
}

__global__ void bar_init_k(unsigned* bar) { bar[threadIdx.x] = 0u; }

// ---- phase: LSTM cell (256 blocks: 4 bgroups x 64 colgroups) ----
__device__ __forceinline__ void cell_phase(SmemU& SU, int bid,
    const float* __restrict__ Wih, const float* __restrict__ Whh,
    const float* __restrict__ bih, const float* __restrict__ bhh,
    const float* emb, const float* h_old, const float* c_old,
    float* h_new, float* c_new)
{
  CellS& S = SU.cell;
  int tid = threadIdx.x;
  int bg = bid >> 6, cg = bid & 63;
  int b0 = bg * 16, d0 = cg * 8;
  const u64* ep = (const u64*)emb;
  const u64* hp = (const u64*)h_old;
  for (int i = tid; i < 4096; i += 256) {          // 16 rows x 256 u64/row
    int b = i >> 8, k2 = i & 255;
    float2 e2 = u64_to_f2(ld_u64c(ep + (size_t)(b0 + b) * 256 + k2));
    float2 h2 = u64_to_f2(ld_u64c(hp + (size_t)(b0 + b) * 256 + k2));
    ((float2*)&S.xs4[b][k2 >> 1])[k2 & 1] = e2;
    ((float2*)&S.hs4[b][k2 >> 1])[k2 & 1] = h2;
  }
  __syncthreads();
  int rl = tid & 31, dl = rl >> 2, gate = rl & 3, bl = tid >> 5;
  int r = gate * 512 + d0 + dl;  // gate order i,f,g,o
  const float4* wi = (const float4*)(Wih + (size_t)r * 512);
  const float4* wh = (const float4*)(Whh + (size_t)r * 512);
  float acc0 = 0.f, acc1 = 0.f;
#pragma unroll 4
  for (int k4 = 0; k4 < 128; k4++) {
    float4 a = wi[k4], w = wh[k4];
    float4 x0 = S.xs4[bl][k4], x1 = S.xs4[bl + 8][k4];
    float4 h0 = S.hs4[bl][k4], h1 = S.hs4[bl + 8][k4];
    acc0 = fmaf(a.x, x0.x, acc0); acc0 = fmaf(a.y, x0.y, acc0);
    acc0 = fmaf(a.z, x0.z, acc0); acc0 = fmaf(a.w, x0.w, acc0);
    acc0 = fmaf(w.x, h0.x, acc0); acc0 = fmaf(w.y, h0.y, acc0);
    acc0 = fmaf(w.z, h0.z, acc0); acc0 = fmaf(w.w, h0.w, acc0);
    acc1 = fmaf(a.x, x1.x, acc1); acc1 = fmaf(a.y, x1.y, acc1);
    acc1 = fmaf(a.z, x1.z, acc1); acc1 = fmaf(a.w, x1.w, acc1);
    acc1 = fmaf(w.x, h1.x, acc1); acc1 = fmaf(w.y, h1.y, acc1);
    acc1 = fmaf(w.z, h1.z, acc1); acc1 = fmaf(w.w, h1.w, acc1);
  }
  float bias = bih[r] + bhh[r];
  S.gv[dl][gate][bl] = acc0 + bias;
  S.gv[dl][gate][bl + 8] = acc1 + bias;
  __syncthreads();
  if (tid < 128) {
    int b = tid & 15, dx = tid >> 4;
    float gi = S.gv[dx][0][b], gf = S.gv[dx][1][b], gg = S.gv[dx][2][b], go = S.gv[dx][3][b];
    size_t idx = (size_t)(b0 + b) * 512 + d0 + dx;
    float c2 = sigm(gf) * ld_f32(c_old + idx) + sigm(gi) * ftanh(gg);
    st_f32(c_new + idx, c2);
    st_f32(h_new + idx, sigm(go) * ftanh(c2));
  }
}

// ---- phase: fused attention, blocks 0..127 = (b, jhalf) ----
__device__ __forceinline__ void attn_phase(SmemU& SU, int bid,
    const float* __restrict__ feats, const float* h, float* ctxp)
{
  AttnS& S = SU.attn;
  int tid = threadIdx.x;
  int b = bid >> 1, jh = bid & 1;
  const float LOG2E = 1.44269504088896f;
  float f0 = feats[b * 512 + tid], f1 = feats[b * 512 + 256 + tid];
  S.fsc[tid] = f0 * LOG2E;
  S.fsc[256 + tid] = f1 * LOG2E;
  {
    float2 h2 = u64_to_f2(ld_u64c((const u64*)h + b * 256 + tid));
    S.hs[2 * tid] = h2.x; S.hs[2 * tid + 1] = h2.y;
  }
  __syncthreads();
  int j = jh * 256 + tid;
  float hj = S.hs[j];
  float Z = 0.f;
#pragma unroll 8
  for (int i = 0; i < 512; i++) Z += exp2f(S.fsc[i] * hj);
  S.wv[tid] = feats[b * 512 + j] / Z;
  __syncthreads();
#pragma unroll
  for (int rep = 0; rep < 2; rep++) {
    int i = rep * 256 + tid;
    float fi = S.fsc[i];
    float acc = 0.f;
#pragma unroll 8
    for (int jj = 0; jj < 256; jj++)
      acc += exp2f(fi * S.hs[jh * 256 + jj]) * S.wv[jj];
    st_f32(ctxp + ((size_t)jh * 64 + b) * 512 + i, acc);
  }
}

// ---- phase: z = [h|ctx] @ Whc.T + bhc (256 blocks) ----
__device__ __forceinline__ void zgemm_phase(SmemU& SU, int bid,
    const float* h, const float* ctxp,
    const float* __restrict__ Whc, const float* __restrict__ bhc, float* z)
{
  ZS& S = SU.z;
  int tid = threadIdx.x;
  int bg = bid >> 6, cg = bid & 63;
  int b0 = bg * 16, d0 = cg * 8;
  const u64* hp = (const u64*)h;
  const u64* cp = (const u64*)ctxp;
  for (int i = tid; i < 4096; i += 256) {
    int b = i >> 8, k2 = i & 255;
    float2 hv = u64_to_f2(ld_u64c(hp + (size_t)(b0 + b) * 256 + k2));
    float2 c0 = u64_to_f2(ld_u64c(cp + ((size_t)0 * 64 + b0 + b) * 256 + k2));
    float2 c1 = u64_to_f2(ld_u64c(cp + ((size_t)1 * 64 + b0 + b) * 256 + k2));
    float2 s; s.x = c0.x + c1.x; s.y = c0.y + c1.y;
    ((float2*)&S.hs4[b][k2 >> 1])[k2 & 1] = hv;
    ((float2*)&S.cs4[b][k2 >> 1])[k2 & 1] = s;
  }
  __syncthreads();
  int dl = tid & 7, b = (tid >> 3) & 15, kh = tid >> 7;
  int dcol = d0 + dl;
  const float4* wr = (const float4*)(Whc + (size_t)dcol * 1024 + (size_t)kh * 512);
  float4 (*src)[128] = kh ? S.cs4 : S.hs4;
  float acc = 0.f;
#pragma unroll 4
  for (int k4 = 0; k4 < 128; k4++) {
    float4 w = wr[k4], x = src[b][k4];
    acc = fmaf(w.x, x.x, acc); acc = fmaf(w.y, x.y, acc);
    acc = fmaf(w.z, x.z, acc); acc = fmaf(w.w, x.w, acc);
  }
  S.zp[kh][b][dl] = acc;
  __syncthreads();
  if (tid < 128) {
    int bb = tid >> 3, dd = tid & 7;
    st_f32(z + (size_t)(b0 + bb) * 512 + d0 + dd, S.zp[0][bb][dd] + S.zp[1][bb][dd] + bhc[d0 + dd]);
  }
}

// ---- phase: LayerNorm + tanh -> emb (f32 coherent) + packed bf16 (blocks 0..63) ----
__device__ __forceinline__ void ln_phase(SmemU& SU, int b,
    const float* z, const float* __restrict__ gamma, const float* __restrict__ beta,
    float* emb, unsigned* emb_bf)
{
  LnS& S = SU.ln;
  int tid = threadIdx.x;
  float2 zv = u64_to_f2(ld_u64c((const u64*)z + b * 256 + tid));
  S.zs[2 * tid] = zv.x; S.zs[2 * tid + 1] = zv.y;
  S.rs[tid] = zv.x + zv.y; S.rq[tid] = zv.x * zv.x + zv.y * zv.y;
  __syncthreads();
  for (int s = 128; s > 0; s >>= 1) {
    if (tid < s) { S.rs[tid] += S.rs[tid + s]; S.rq[tid] += S.rq[tid + s]; }
    __syncthreads();
  }
  float mean = S.rs[0] * (1.0f / 512.0f);
  float var = S.rq[0] * (1.0f / 512.0f) - mean * mean;
  float rstd = rsqrtf(var + 1e-5f);
  float e0 = ftanh((S.zs[2 * tid] - mean) * rstd * gamma[2 * tid] + beta[2 * tid]);
  float e1 = ftanh((S.zs[2 * tid + 1] - mean) * rstd * gamma[2 * tid + 1] + beta[2 * tid + 1]);
  st_u64c((u64*)emb + b * 256 + tid, f2_to_u64(e0, e1));
  st_u32(emb_bf + b * 256 + tid, (unsigned)f2bf(e0) | ((unsigned)f2bf(e1) << 16));
}

// ---- one logits tile: A from LDS, B (vocab) cached, MFMA 16x16x32 bf16 ----
__device__ __forceinline__ void logits_tile_lds(SmemU& SU,
    const unsigned short* __restrict__ vocab_bf, const float* __restrict__ vbias,
    float* __restrict__ out, int q)
{
  if (q >= NTILE) return;
  int n0 = q * 64;
  int w = threadIdx.x >> 6, l = threadIdx.x & 63;
  int lm = l & 15, kb = l >> 4;
  int m = w * 16 + lm;
  f32x4 acc[4] = {};
  const unsigned short* arow = SU.ebf + m * 520 + kb * 8;
#pragma unroll 4
  for (int kt = 0; kt < 16; kt++) {
    short8 a = *(const short8*)(arow + kt * 32);
#pragma unroll
    for (int nt = 0; nt < 4; nt++) {
      const short8* bp = (const short8*)(vocab_bf + (size_t)(n0 + nt * 16 + lm) * 512);
      short8 bv = bp[kt * 4 + kb];
      acc[nt] = __builtin_amdgcn_mfma_f32_16x16x32_bf16(a, bv, acc[nt], 0, 0, 0);
    }
  }
  int rbase = w * 16 + kb * 4;  // C/D: col = lane&15, row = (lane>>4)*4 + reg
#pragma unroll
  for (int nt = 0; nt < 4; nt++) {
    int v = n0 + nt * 16 + lm;
    float bias = vbias[v];
#pragma unroll
    for (int r = 0; r < 4; r++) {
      out[(size_t)(rbase + r) * 32000 + v] = acc[nt][r] + bias;
    }
  }
}

// stage emb_bf (64KB) coherently into padded LDS, then run tiles
__device__ __forceinline__ void logits_phase(SmemU& SU, const unsigned* ebf_prev,
    const unsigned short* __restrict__ vocab_bf, const float* __restrict__ vbias,
    float* __restrict__ out, int nt0, int ntiles)
{
  int tid = threadIdx.x;
  const u64* src = (const u64*)ebf_prev;
  for (int i = tid; i < 8192; i += 256) {       // 64 rows x 128 u64/row
    int mm = i >> 7, j = i & 127;
    u64 v = ld_u64c(src + i);
    *(u64*)&SU.ebf[mm * 520 + 4 * j] = v;
  }
  __syncthreads();
  for (int q = 0; q < ntiles; q++)
    logits_tile_lds(SU, vocab_bf, vbias, out, nt0 + q);
}

// ---- the persistent kernel ----
__global__ __launch_bounds__(256, 1) void persist_k(
    const float* __restrict__ feats, const float* __restrict__ Wih, const float* __restrict__ Whh,
    const float* __restrict__ bih, const float* __restrict__ bhh,
    const float* __restrict__ Whc, const float* __restrict__ bhc,
    const float* __restrict__ gam, const float* __restrict__ bet,
    const float* __restrict__ vemb, const float* __restrict__ vbias,
    unsigned short* vocab_bf, float* hA, float* hB, float* cA, float* cB,
    float* emb, float* zb, unsigned* ebf0, unsigned* ebf1,
    float* ctxp, float* out, unsigned* bar)
{
  __shared__ SmemU SU;
  const int bid = blockIdx.x, tid = threadIdx.x;
  unsigned epoch = 0;

  // phase V: vocab fp32 -> bf16 (sc1 write-through to LLC) + state init
  {
    const float4* vp = (const float4*)vemb;
    u64* ov = (u64*)vocab_bf;
    for (int i = bid * NTHR + tid; i < VV * DD / 4; i += GRID * NTHR) {
      float4 x = vp[i];
      u64 y = (u64)f2bf(x.x) | ((u64)f2bf(x.y) << 16) | ((u64)f2bf(x.z) << 32) | ((u64)f2bf(x.w) << 48);
      st_u64c(ov + i, y);
    }
    for (int i = bid * NTHR + tid; i < BB * DD; i += GRID * NTHR) {
      float f = feats[i];
      st_f32(hA + i, f); st_f32(cA + i, f);
      st_f32(emb + i, vemb[i & (DD - 1)]);
    }
  }
  gridsync(bar, epoch);

  for (int t = 0; t < TT; t++) {
    float* ho = (t & 1) ? hB : hA; float* hn = (t & 1) ? hA : hB;
    float* co = (t & 1) ? cB : cA; float* cn = (t & 1) ? cA : cB;
    unsigned* ebf_cur  = (t & 1) ? ebf1 : ebf0;
    unsigned* ebf_prev = (t & 1) ? ebf0 : ebf1;
    float* out_prev = out + (size_t)(t - 1) * BB * VV;

    // P1: cell(t) — all blocks
    cell_phase(SU, bid, Wih, Whh, bih, bhh, emb, ho, co, hn, cn);
    gridsync(bar, epoch);

    // P2: attn(t) on blocks 0..127; logits(t-1) tiles 0..255 on blocks 128..255
    if (bid < 128) {
      attn_phase(SU, bid, feats, hn, ctxp);
    } else if (t >= 1) {
      logits_phase(SU, ebf_prev, vocab_bf, vbias, out_prev, (bid - 128) * 2, 2);
    }
    gridsync(bar, epoch);

    // P3: zgemm(t) — all blocks
    zgemm_phase(SU, bid, hn, ctxp, Whc, bhc, zb);
    gridsync(bar, epoch);

    // P4: ln(t) on blocks 0..63; logits(t-1) tiles 256..499 on blocks 64..255
    if (bid < 64) {
      ln_phase(SU, bid, zb, gam, bet, emb, ebf_cur);
    } else if (t >= 1) {
      int idx = bid - 64;
      if (idx < 52) logits_phase(SU, ebf_prev, vocab_bf, vbias, out_prev, 256 + 2 * idx, 2);
      else          logits_phase(SU, ebf_prev, vocab_bf, vbias, out_prev, 360 + (idx - 52), 1);
    }
    gridsync(bar, epoch);
  }

  // drain: logits(31) — all blocks, 2 tiles each (tail guarded inside)
  logits_phase(SU, ebf1, vocab_bf, vbias, out + (size_t)(TT - 1) * BB * VV, bid * 2, 2);
}

extern "C" void kernel_launch(void* const* d_in, const int* in_sizes, int n_in,
                              void* d_out, int out_size, void* d_ws, size_t ws_size,
                              hipStream_t stream) {
  const float* feats = (const float*)d_in[0];
  const float* Wih   = (const float*)d_in[1];
  const float* Whh   = (const float*)d_in[2];
  const float* bih   = (const float*)d_in[3];
  const float* bhh   = (const float*)d_in[4];
  const float* Whc   = (const float*)d_in[5];
  const float* bhc   = (const float*)d_in[6];
  const float* gam   = (const float*)d_in[7];
  const float* bet   = (const float*)d_in[8];
  const float* vemb  = (const float*)d_in[9];
  const float* vbias = (const float*)d_in[10];
  float* out = (float*)d_out;

  char* p = (char*)d_ws;
  unsigned short* vocab_bf = (unsigned short*)p; p += (size_t)VV * DD * 2;  // 32.77 MB
  float* hA  = (float*)p; p += BB * DD * 4;
  float* hB  = (float*)p; p += BB * DD * 4;
  float* cA  = (float*)p; p += BB * DD * 4;
  float* cB  = (float*)p; p += BB * DD * 4;
  float* emb = (float*)p; p += BB * DD * 4;
  float* zb  = (float*)p; p += BB * DD * 4;
  unsigned* ebf0 = (unsigned*)p; p += BB * DD * 2;
  unsigned* ebf1 = (unsigned*)p; p += BB * DD * 2;
  float* ctxp = (float*)p; p += (size_t)2 * BB * DD * 4;
  unsigned* bar = (unsigned*)p; p += 256;

  bar_init_k<<<1, 64, 0, stream>>>(bar);
  persist_k<<<GRID, NTHR, 0, stream>>>(feats, Wih, Whh, bih, bhh, Whc, bhc, gam, bet,
                                       vemb, vbias, vocab_bf, hA, hB, cA, cB, emb, zb,
                                       ebf0, ebf1, ctxp, out, bar);
}